// Round 12
// baseline (106.816 us; speedup 1.0000x reference)
//
#include <hip/hip_runtime.h>
#include <cstdint>
#include <cstddef>

#define NN 8192
#define INF 512
#define OUTF 64
#define ALPHA 0.2f
#define NSPLIT 8
#define JSPLIT (NN / NSPLIT)   // 1024

typedef short bf16x8 __attribute__((ext_vector_type(8)));
typedef float f32x4 __attribute__((ext_vector_type(4)));

static __device__ inline unsigned short f2bf(float f) {
    unsigned u = __builtin_bit_cast(unsigned, f);
    unsigned r = (u + 0x7FFFu + ((u >> 16) & 1u)) >> 16;
    return (unsigned short)r;
}

// ---------------------------------------------------------------------------
// Kernel 1: Wh = x @ W (proven GEMM path, standalone). Writes Asw (MFMA-A-
// swizzled bf16 Wh), U = exp(0.8 s1), E2p = exp(s2), E2n = exp(0.2 s2).
// ---------------------------------------------------------------------------
__global__ __launch_bounds__(256) void k1_gemm(
    const float* __restrict__ x, const float* __restrict__ W,
    const float* __restrict__ a, unsigned short* __restrict__ Asw,
    float* __restrict__ U, float* __restrict__ E2p, float* __restrict__ E2n)
{
    const int tid = threadIdx.x;
    const int i0  = blockIdx.x * 16;
    const int w   = __builtin_amdgcn_readfirstlane(tid >> 6);
    const int c   = tid & 63;

    const float* xr = x + (size_t)(i0 + 4 * w) * INF;
    const float* Wc = W + c;
    float acc[4] = {0.f, 0.f, 0.f, 0.f};

    #pragma unroll 4
    for (int kk = 0; kk < 128; ++kk) {
        const float4 x0 = *(const float4*)(xr + 0 * INF + kk * 4);
        const float4 x1 = *(const float4*)(xr + 1 * INF + kk * 4);
        const float4 x2 = *(const float4*)(xr + 2 * INF + kk * 4);
        const float4 x3 = *(const float4*)(xr + 3 * INF + kk * 4);
        const float w0 = Wc[(kk * 4 + 0) * OUTF];
        const float w1 = Wc[(kk * 4 + 1) * OUTF];
        const float w2 = Wc[(kk * 4 + 2) * OUTF];
        const float w3 = Wc[(kk * 4 + 3) * OUTF];
        acc[0] = fmaf(x0.x, w0, fmaf(x0.y, w1, fmaf(x0.z, w2, fmaf(x0.w, w3, acc[0]))));
        acc[1] = fmaf(x1.x, w0, fmaf(x1.y, w1, fmaf(x1.z, w2, fmaf(x1.w, w3, acc[1]))));
        acc[2] = fmaf(x2.x, w0, fmaf(x2.y, w1, fmaf(x2.z, w2, fmaf(x2.w, w3, acc[2]))));
        acc[3] = fmaf(x3.x, w0, fmaf(x3.y, w1, fmaf(x3.z, w2, fmaf(x3.w, w3, acc[3]))));
    }

    const float a1c = a[c];
    const float a2c = a[64 + c];
    #pragma unroll
    for (int q = 0; q < 4; ++q) {
        float v1 = acc[q] * a1c;
        float v2 = acc[q] * a2c;
        #pragma unroll
        for (int m = 32; m; m >>= 1) {
            v1 += __shfl_xor(v1, m, 64);
            v2 += __shfl_xor(v2, m, 64);
        }
        if (c == 0) {
            const int i = i0 + 4 * w + q;
            U[i]   = __expf((1.0f - ALPHA) * v1);
            E2p[i] = __expf(v2);
            E2n[i] = __expf(ALPHA * v2);
        }
    }

    const int i   = i0 + 4 * w;
    const int jt  = i >> 5;
    const int sub = (i >> 3) & 3;
    const int e0  = i & 7;
    ushort4 pk;
    pk.x = f2bf(acc[0]); pk.y = f2bf(acc[1]);
    pk.z = f2bf(acc[2]); pk.w = f2bf(acc[3]);
    *(ushort4*)&Asw[((size_t)(c >> 4) * 256 + jt) * 512 + ((c & 15) + 16 * sub) * 8 + e0] = pk;
}

// ---------------------------------------------------------------------------
// Kernel 2 (fused): ONE pass over adj with the attention computed in-flight.
// Block = 32-row i-tile x 1024-col split (2048 blocks, 4 waves).
// Per 128-col superstep: T14 staging (loads for ss+1 issued during compute of
// ss), LDS [32][132] as the transpose medium, each wave one 32-j MFMA window.
// Epilogue: cross-wave accumulator reduce in LDS, single Opart/lpart write.
// No bitmask intermediate; adj ints used directly as mask.
// ---------------------------------------------------------------------------
__global__ __launch_bounds__(256) void k2_fused(
    const int* __restrict__ adj, const unsigned short* __restrict__ Asw,
    const float* __restrict__ Ug, const float* __restrict__ E2pg,
    const float* __restrict__ E2ng,
    float* __restrict__ Opart, float* __restrict__ lpart)
{
    __shared__ char smem[33280];
    int   (*stage)[132] = (int(*)[132])smem;     // [32][132] = 16.9 KB
    float* red  = (float*)smem;                  // [4][2048] = 32 KB (reuse)
    float* redl = (float*)(smem + 32768);        // [4][32]

    const int tid   = threadIdx.x;
    const int l     = tid & 63;
    const int w     = tid >> 6;
    const int split = blockIdx.x & (NSPLIT - 1);
    const int i0    = (blockIdx.x >> 3) * 32;
    const int jbase = split * JSPLIT;

    const int il  = l & 15;
    const int kg  = l >> 4;
    const int kg8 = kg * 8;

    const float ua = Ug[i0 + il];
    const float ub = Ug[i0 + 16 + il];

    f32x4 a00 = {0,0,0,0}, a01 = {0,0,0,0}, a10 = {0,0,0,0}, a11 = {0,0,0,0};
    f32x4 a20 = {0,0,0,0}, a21 = {0,0,0,0}, a30 = {0,0,0,0}, a31 = {0,0,0,0};
    float rsA = 0.f, rsB = 0.f;

    // staging role: thread covers rows {0,8,16,24}+ (tid>>5), int4-col tid&31
    const int srow = tid >> 5;
    const int sc4  = tid & 31;
    const int* abase = adj + (size_t)(i0 + srow) * NN + jbase + sc4 * 4;

    int4 vreg0, vreg1, vreg2, vreg3;
    vreg0 = *(const int4*)(abase + (size_t)0  * NN);
    vreg1 = *(const int4*)(abase + (size_t)8  * NN);
    vreg2 = *(const int4*)(abase + (size_t)16 * NN);
    vreg3 = *(const int4*)(abase + (size_t)24 * NN);

#define SCM(UU, EP, EN, M) ((M) ? fmaxf((UU) * (EP), (EN)) : 0.f)

    for (int ss = 0; ss < NSPLIT == 0 ? 0 : 8; ++ss) {   // 8 supersteps of 128
        __syncthreads();                       // prev compute done with stage
        *(int4*)&stage[srow +  0][sc4 * 4] = vreg0;
        *(int4*)&stage[srow +  8][sc4 * 4] = vreg1;
        *(int4*)&stage[srow + 16][sc4 * 4] = vreg2;
        *(int4*)&stage[srow + 24][sc4 * 4] = vreg3;
        if (ss < 7) {                          // issue next-superstep loads now
            const int* ab = abase + (ss + 1) * 128;
            vreg0 = *(const int4*)(ab + (size_t)0  * NN);
            vreg1 = *(const int4*)(ab + (size_t)8  * NN);
            vreg2 = *(const int4*)(ab + (size_t)16 * NN);
            vreg3 = *(const int4*)(ab + (size_t)24 * NN);
        }
        __syncthreads();                       // stage ready

        // ---- compute: wave w owns local cols [w*32, w*32+32) ----
        const int wc = w * 32 + kg8;
        const int4 m0a = *(const int4*)&stage[il][wc];
        const int4 m0b = *(const int4*)&stage[il][wc + 4];
        const int4 m1a = *(const int4*)&stage[il + 16][wc];
        const int4 m1b = *(const int4*)&stage[il + 16][wc + 4];

        const int jg = jbase + ss * 128 + w * 32;        // window global j
        const float* ep = E2pg + jg + kg8;
        const float* en = E2ng + jg + kg8;
        const float4 P0 = *(const float4*)(ep);
        const float4 P1 = *(const float4*)(ep + 4);
        const float4 N0 = *(const float4*)(en);
        const float4 N1 = *(const float4*)(en + 4);

        const unsigned short* Ap = Asw + (size_t)(jg >> 5) * 512 + l * 8;
        const bf16x8 A0 = *(const bf16x8*)(Ap);
        const bf16x8 A1 = *(const bf16x8*)(Ap + 131072);
        const bf16x8 A2 = *(const bf16x8*)(Ap + 262144);
        const bf16x8 A3 = *(const bf16x8*)(Ap + 393216);

        const float p0 = SCM(ua, P0.x, N0.x, m0a.x);
        const float p1 = SCM(ua, P0.y, N0.y, m0a.y);
        const float p2 = SCM(ua, P0.z, N0.z, m0a.z);
        const float p3 = SCM(ua, P0.w, N0.w, m0a.w);
        const float p4 = SCM(ua, P1.x, N1.x, m0b.x);
        const float p5 = SCM(ua, P1.y, N1.y, m0b.y);
        const float p6 = SCM(ua, P1.z, N1.z, m0b.z);
        const float p7 = SCM(ua, P1.w, N1.w, m0b.w);
        const float q0 = SCM(ub, P0.x, N0.x, m1a.x);
        const float q1 = SCM(ub, P0.y, N0.y, m1a.y);
        const float q2 = SCM(ub, P0.z, N0.z, m1a.z);
        const float q3 = SCM(ub, P0.w, N0.w, m1a.w);
        const float q4 = SCM(ub, P1.x, N1.x, m1b.x);
        const float q5 = SCM(ub, P1.y, N1.y, m1b.y);
        const float q6 = SCM(ub, P1.z, N1.z, m1b.z);
        const float q7 = SCM(ub, P1.w, N1.w, m1b.w);

        rsA += ((p0 + p1) + (p2 + p3)) + ((p4 + p5) + (p6 + p7));
        rsB += ((q0 + q1) + (q2 + q3)) + ((q4 + q5) + (q6 + q7));

        uint4 wa, wb;
        asm("v_cvt_pk_bf16_f32 %0, %1, %2" : "=v"(wa.x) : "v"(p0), "v"(p1));
        asm("v_cvt_pk_bf16_f32 %0, %1, %2" : "=v"(wa.y) : "v"(p2), "v"(p3));
        asm("v_cvt_pk_bf16_f32 %0, %1, %2" : "=v"(wa.z) : "v"(p4), "v"(p5));
        asm("v_cvt_pk_bf16_f32 %0, %1, %2" : "=v"(wa.w) : "v"(p6), "v"(p7));
        asm("v_cvt_pk_bf16_f32 %0, %1, %2" : "=v"(wb.x) : "v"(q0), "v"(q1));
        asm("v_cvt_pk_bf16_f32 %0, %1, %2" : "=v"(wb.y) : "v"(q2), "v"(q3));
        asm("v_cvt_pk_bf16_f32 %0, %1, %2" : "=v"(wb.z) : "v"(q4), "v"(q5));
        asm("v_cvt_pk_bf16_f32 %0, %1, %2" : "=v"(wb.w) : "v"(q6), "v"(q7));
        const bf16x8 BA = __builtin_bit_cast(bf16x8, wa);
        const bf16x8 BB = __builtin_bit_cast(bf16x8, wb);

        a00 = __builtin_amdgcn_mfma_f32_16x16x32_bf16(A0, BA, a00, 0, 0, 0);
        a01 = __builtin_amdgcn_mfma_f32_16x16x32_bf16(A0, BB, a01, 0, 0, 0);
        a10 = __builtin_amdgcn_mfma_f32_16x16x32_bf16(A1, BA, a10, 0, 0, 0);
        a11 = __builtin_amdgcn_mfma_f32_16x16x32_bf16(A1, BB, a11, 0, 0, 0);
        a20 = __builtin_amdgcn_mfma_f32_16x16x32_bf16(A2, BA, a20, 0, 0, 0);
        a21 = __builtin_amdgcn_mfma_f32_16x16x32_bf16(A2, BB, a21, 0, 0, 0);
        a30 = __builtin_amdgcn_mfma_f32_16x16x32_bf16(A3, BA, a30, 0, 0, 0);
        a31 = __builtin_amdgcn_mfma_f32_16x16x32_bf16(A3, BB, a31, 0, 0, 0);
    }
#undef SCM

    // ---- cross-wave reduce (LDS reuses stage) ----
    rsA += __shfl_xor(rsA, 16, 64);
    rsA += __shfl_xor(rsA, 32, 64);
    rsB += __shfl_xor(rsB, 16, 64);
    rsB += __shfl_xor(rsB, 32, 64);

    __syncthreads();                // all waves done reading stage
    float* rw = red + w * 2048 + l * 32;
    *(float4*)(rw + 0)  = *(float4*)&a00;   // q0 h0
    *(float4*)(rw + 4)  = *(float4*)&a01;   // q0 h1
    *(float4*)(rw + 8)  = *(float4*)&a10;
    *(float4*)(rw + 12) = *(float4*)&a11;
    *(float4*)(rw + 16) = *(float4*)&a20;
    *(float4*)(rw + 20) = *(float4*)&a21;
    *(float4*)(rw + 24) = *(float4*)&a30;
    *(float4*)(rw + 28) = *(float4*)&a31;
    if (l < 16) {
        redl[w * 32 + il]      = rsA;
        redl[w * 32 + 16 + il] = rsB;
    }
    __syncthreads();

    // thread t: lane-slot l2 = t>>2, quarter q2 = t&3; sum 4 waves, write.
    const int l2  = tid >> 2, q2 = tid & 3;
    const int il2 = l2 & 15, kg2 = l2 >> 4;
    #pragma unroll
    for (int h = 0; h < 2; ++h) {
        const int idx = l2 * 32 + q2 * 8 + h * 4;
        float4 s0 = *(float4*)(red + idx);
        float4 s1 = *(float4*)(red + 2048 + idx);
        float4 s2 = *(float4*)(red + 4096 + idx);
        float4 s3 = *(float4*)(red + 6144 + idx);
        float4 s;
        s.x = (s0.x + s1.x) + (s2.x + s3.x);
        s.y = (s0.y + s1.y) + (s2.y + s3.y);
        s.z = (s0.z + s1.z) + (s2.z + s3.z);
        s.w = (s0.w + s1.w) + (s2.w + s3.w);
        *(float4*)&Opart[((size_t)split * NN + i0 + h * 16 + il2) * OUTF
                         + q2 * 16 + kg2 * 4] = s;
    }
    if (tid < 32)
        lpart[(size_t)split * NN + i0 + tid] =
            (redl[tid] + redl[32 + tid]) + (redl[64 + tid] + redl[96 + tid]);
}

// ---------------------------------------------------------------------------
// Kernel 3: combine the 8 j-split partials and normalize.
// ---------------------------------------------------------------------------
__global__ __launch_bounds__(256) void k3_combine(
    const float* __restrict__ Opart, const float* __restrict__ lpart,
    float* __restrict__ out)
{
    const int f4 = blockIdx.x * 256 + threadIdx.x;
    const int i  = f4 >> 4;

    float4 r = {0.f, 0.f, 0.f, 0.f};
    float  lsum = 0.f;
    #pragma unroll
    for (int s = 0; s < NSPLIT; ++s) {
        float4 o = *(const float4*)&Opart[(size_t)s * NN * OUTF + (size_t)f4 * 4];
        r.x += o.x; r.y += o.y; r.z += o.z; r.w += o.w;
        lsum += lpart[(size_t)s * NN + i];
    }
    float inv = 1.0f / lsum;
    r.x *= inv; r.y *= inv; r.z *= inv; r.w *= inv;
    *(float4*)&out[(size_t)f4 * 4] = r;
}

extern "C" void kernel_launch(void* const* d_in, const int* in_sizes, int n_in,
                              void* d_out, int out_size, void* d_ws, size_t ws_size,
                              hipStream_t stream) {
    const float* x   = (const float*)d_in[0];
    const int*   adj = (const int*)d_in[1];
    const float* W   = (const float*)d_in[2];
    const float* a   = (const float*)d_in[3];
    float* out = (float*)d_out;

    char* ws = (char*)d_ws;
    unsigned short* Asw = (unsigned short*)ws;                        // 1 MB
    float* U     = (float*)(ws + (1 << 20));                          // 32 KB
    float* E2p   = (float*)(ws + (1 << 20) + 32768);                  // 32 KB
    float* E2n   = (float*)(ws + (1 << 20) + 65536);                  // 32 KB
    float* lpart = (float*)(ws + (1 << 20) + 98304);                  // 256 KB
    float* Opart = (float*)(ws + (1 << 20) + 98304 + 262144);         // 16 MB

    k1_gemm<<<512, 256, 0, stream>>>(x, W, a, Asw, U, E2p, E2n);
    k2_fused<<<2048, 256, 0, stream>>>(adj, Asw, U, E2p, E2n, Opart, lpart);
    k3_combine<<<512, 256, 0, stream>>>(Opart, lpart, out);
}